// Round 1
// baseline (913.807 us; speedup 1.0000x reference)
//
#include <hip/hip_runtime.h>

#define TB 256

static __device__ __forceinline__ float leaky(float x) {
  return x > 0.f ? x : 0.2f * x;
}

// ---------------- CSR build ----------------

__global__ void k_hist(const int* __restrict__ dstA, int* __restrict__ deg, int E) {
  int i = blockIdx.x * blockDim.x + threadIdx.x;
  if (i < E) atomicAdd(&deg[dstA[i]], 1);
}

__global__ void k_scan(const int* __restrict__ deg, int* __restrict__ rowStart,
                       int* __restrict__ cursor, int N) {
  __shared__ int sums[1024];
  const int t = threadIdx.x;
  const int chunk = (N + 1023) / 1024;
  const int base = t * chunk;
  int s = 0;
  for (int i = 0; i < chunk; ++i) {
    int idx = base + i;
    if (idx < N) s += deg[idx];
  }
  sums[t] = s;
  __syncthreads();
  for (int off = 1; off < 1024; off <<= 1) {
    int v = (t >= off) ? sums[t - off] : 0;
    __syncthreads();
    sums[t] += v;
    __syncthreads();
  }
  int excl = (t == 0) ? 0 : sums[t - 1];
  for (int i = 0; i < chunk; ++i) {
    int idx = base + i;
    if (idx < N) {
      rowStart[idx] = excl;
      cursor[idx] = excl;
      excl += deg[idx];
    }
  }
}

__global__ void k_fill(const int* __restrict__ srcA, const int* __restrict__ dstA,
                       int* __restrict__ cursor, int* __restrict__ colIdx, int E) {
  int i = blockIdx.x * blockDim.x + threadIdx.x;
  if (i < E) {
    int d = dstA[i];
    int pos = atomicAdd(&cursor[d], 1);
    colIdx[pos] = srcA[i];
  }
}

// ---------------- node transform: h = x@W, alpha_src/dst ----------------

template <int IN, int H, int C>
__global__ void k_node(const float* __restrict__ xin, const float* __restrict__ W,
                       const float* __restrict__ a_src, const float* __restrict__ a_dst,
                       float* __restrict__ hout, float* __restrict__ as_,
                       float* __restrict__ ad_, int N) {
  constexpr int OUT = H * C;
  __shared__ float Ws[IN * OUT];
  __shared__ float As[OUT], Ad[OUT];
  for (int i = threadIdx.x; i < IN * OUT; i += blockDim.x) Ws[i] = W[i];
  if (threadIdx.x < OUT) {
    As[threadIdx.x] = a_src[threadIdx.x];
    Ad[threadIdx.x] = a_dst[threadIdx.x];
  }
  __syncthreads();
  int n = blockIdx.x * blockDim.x + threadIdx.x;
  if (n >= N) return;
  float acc[OUT];
#pragma unroll
  for (int j = 0; j < OUT; ++j) acc[j] = 0.f;
  const float4* x4 = reinterpret_cast<const float4*>(xin + (size_t)n * IN);
#pragma unroll
  for (int k4 = 0; k4 < IN / 4; ++k4) {
    float4 xv = x4[k4];
#pragma unroll
    for (int j = 0; j < OUT; ++j) {
      acc[j] += xv.x * Ws[(4 * k4 + 0) * OUT + j];
      acc[j] += xv.y * Ws[(4 * k4 + 1) * OUT + j];
      acc[j] += xv.z * Ws[(4 * k4 + 2) * OUT + j];
      acc[j] += xv.w * Ws[(4 * k4 + 3) * OUT + j];
    }
  }
  float4* h4 = reinterpret_cast<float4*>(hout + (size_t)n * OUT);
#pragma unroll
  for (int j4 = 0; j4 < OUT / 4; ++j4) {
    float4 v;
    v.x = acc[4 * j4 + 0];
    v.y = acc[4 * j4 + 1];
    v.z = acc[4 * j4 + 2];
    v.w = acc[4 * j4 + 3];
    h4[j4] = v;
  }
#pragma unroll
  for (int hh = 0; hh < H; ++hh) {
    float ss = 0.f, dd = 0.f;
#pragma unroll
    for (int c = 0; c < C; ++c) {
      ss += acc[hh * C + c] * As[hh * C + c];
      dd += acc[hh * C + c] * Ad[hh * C + c];
    }
    as_[n * H + hh] = ss;
    ad_[n * H + hh] = dd;
  }
}

// ---------------- edge aggregation: online softmax over in-edges ----------------

template <int H, int C, bool RELU>
__global__ void k_edge(const int* __restrict__ rowStart, const int* __restrict__ deg,
                       const int* __restrict__ colIdx, const float* __restrict__ hfeat,
                       const float* __restrict__ as_, const float* __restrict__ ad_,
                       const float* __restrict__ bias, float* __restrict__ out, int N) {
  constexpr int OUT = H * C;
  int n = blockIdx.x * blockDim.x + threadIdx.x;
  if (n >= N) return;
  float adv[H], m[H], s[H], acc[OUT];
#pragma unroll
  for (int hh = 0; hh < H; ++hh) {
    adv[hh] = ad_[n * H + hh];
    float e = leaky(as_[n * H + hh] + adv[hh]);  // self-loop term
    m[hh] = e;
    s[hh] = 1.f;
  }
  const float4* hn4 = reinterpret_cast<const float4*>(hfeat + (size_t)n * OUT);
#pragma unroll
  for (int j4 = 0; j4 < OUT / 4; ++j4) {
    float4 v = hn4[j4];
    acc[4 * j4 + 0] = v.x;
    acc[4 * j4 + 1] = v.y;
    acc[4 * j4 + 2] = v.z;
    acc[4 * j4 + 3] = v.w;
  }
  const int start = rowStart[n];
  const int cnt = deg[n];
  for (int i = 0; i < cnt; ++i) {
    int src = colIdx[start + i];
    float hv[OUT];
    const float4* hs4 = reinterpret_cast<const float4*>(hfeat + (size_t)src * OUT);
#pragma unroll
    for (int j4 = 0; j4 < OUT / 4; ++j4) {
      float4 v = hs4[j4];
      hv[4 * j4 + 0] = v.x;
      hv[4 * j4 + 1] = v.y;
      hv[4 * j4 + 2] = v.z;
      hv[4 * j4 + 3] = v.w;
    }
#pragma unroll
    for (int hh = 0; hh < H; ++hh) {
      float e = leaky(as_[src * H + hh] + adv[hh]);
      float nm = fmaxf(m[hh], e);
      float f = __expf(m[hh] - nm);
      float p = __expf(e - nm);
      m[hh] = nm;
      s[hh] = s[hh] * f + p;
#pragma unroll
      for (int c = 0; c < C; ++c) acc[hh * C + c] = acc[hh * C + c] * f + p * hv[hh * C + c];
    }
  }
#pragma unroll
  for (int hh = 0; hh < H; ++hh) {
    float inv = 1.f / (s[hh] + 1e-16f);
#pragma unroll
    for (int c = 0; c < C; ++c) {
      float v = acc[hh * C + c] * inv + bias[hh * C + c];
      if (RELU) v = fmaxf(v, 0.f);
      out[n * OUT + hh * C + c] = v;
    }
  }
}

// ---------------- layer-3 edge aggregation + fused classifier ----------------

__global__ void k_edge3(const int* __restrict__ rowStart, const int* __restrict__ deg,
                        const int* __restrict__ colIdx, const float* __restrict__ hfeat,
                        const float* __restrict__ as_, const float* __restrict__ ad_,
                        const float* __restrict__ b3, const float* __restrict__ Wc,
                        const float* __restrict__ bc, float* __restrict__ out, int N) {
  int n = blockIdx.x * blockDim.x + threadIdx.x;
  if (n >= N) return;
  float adv = ad_[n];
  float e0 = leaky(as_[n] + adv);
  float m = e0, s = 1.f;
  float4 hn = reinterpret_cast<const float4*>(hfeat)[n];
  float acc0 = hn.x, acc1 = hn.y, acc2 = hn.z, acc3 = hn.w;
  const int start = rowStart[n];
  const int cnt = deg[n];
  for (int i = 0; i < cnt; ++i) {
    int src = colIdx[start + i];
    float4 hv = reinterpret_cast<const float4*>(hfeat)[src];
    float e = leaky(as_[src] + adv);
    float nm = fmaxf(m, e);
    float f = __expf(m - nm);
    float p = __expf(e - nm);
    m = nm;
    s = s * f + p;
    acc0 = acc0 * f + p * hv.x;
    acc1 = acc1 * f + p * hv.y;
    acc2 = acc2 * f + p * hv.z;
    acc3 = acc3 * f + p * hv.w;
  }
  float inv = 1.f / (s + 1e-16f);
  float o0 = acc0 * inv + b3[0];
  float o1 = acc1 * inv + b3[1];
  float o2 = acc2 * inv + b3[2];
  float o3 = acc3 * inv + b3[3];
  float r0 = o0 * Wc[0] + o1 * Wc[2] + o2 * Wc[4] + o3 * Wc[6] + bc[0];
  float r1 = o0 * Wc[1] + o1 * Wc[3] + o2 * Wc[5] + o3 * Wc[7] + bc[1];
  out[(size_t)n * 2 + 0] = r0;
  out[(size_t)n * 2 + 1] = r1;
}

// ---------------- launch ----------------

extern "C" void kernel_launch(void* const* d_in, const int* in_sizes, int n_in,
                              void* d_out, int out_size, void* d_ws, size_t ws_size,
                              hipStream_t stream) {
  const float* x    = (const float*)d_in[0];
  const int*   ei   = (const int*)d_in[1];
  const float* W1   = (const float*)d_in[2];
  const float* as1w = (const float*)d_in[3];
  const float* ad1w = (const float*)d_in[4];
  const float* b1   = (const float*)d_in[5];
  const float* W2   = (const float*)d_in[6];
  const float* as2w = (const float*)d_in[7];
  const float* ad2w = (const float*)d_in[8];
  const float* b2   = (const float*)d_in[9];
  const float* W3   = (const float*)d_in[10];
  const float* as3w = (const float*)d_in[11];
  const float* ad3w = (const float*)d_in[12];
  const float* b3   = (const float*)d_in[13];
  const float* Wc   = (const float*)d_in[14];
  const float* bc   = (const float*)d_in[15];
  float* out = (float*)d_out;

  const int N = in_sizes[0] / 128;
  const int E = in_sizes[1] / 2;
  const int* srcA = ei;
  const int* dstA = ei + E;

  char* p = (char*)d_ws;
  auto alloc = [&](size_t bytes) -> void* {
    void* r = (void*)p;
    p += (bytes + 255) & ~(size_t)255;
    return r;
  };
  int* deg      = (int*)alloc((size_t)N * 4);
  int* rowStart = (int*)alloc((size_t)N * 4);
  int* cursor   = (int*)alloc((size_t)N * 4);
  int* colIdx   = (int*)alloc((size_t)E * 4);
  float* h1  = (float*)alloc((size_t)N * 16 * 4);
  float* as1 = (float*)alloc((size_t)N * 2 * 4);
  float* ad1 = (float*)alloc((size_t)N * 2 * 4);
  float* o1  = (float*)alloc((size_t)N * 16 * 4);
  float* h2  = (float*)alloc((size_t)N * 8 * 4);
  float* as2 = (float*)alloc((size_t)N * 2 * 4);
  float* ad2 = (float*)alloc((size_t)N * 2 * 4);
  float* o2  = (float*)alloc((size_t)N * 8 * 4);
  float* h3  = (float*)alloc((size_t)N * 4 * 4);
  float* as3 = (float*)alloc((size_t)N * 4);
  float* ad3 = (float*)alloc((size_t)N * 4);

  hipMemsetAsync(deg, 0, (size_t)N * 4, stream);

  const int eb = (E + TB - 1) / TB;
  const int nb = (N + TB - 1) / TB;

  k_hist<<<eb, TB, 0, stream>>>(dstA, deg, E);
  k_scan<<<1, 1024, 0, stream>>>(deg, rowStart, cursor, N);
  k_fill<<<eb, TB, 0, stream>>>(srcA, dstA, cursor, colIdx, E);

  // layer 1: in=128, H=2, C=8
  k_node<128, 2, 8><<<nb, TB, 0, stream>>>(x, W1, as1w, ad1w, h1, as1, ad1, N);
  k_edge<2, 8, true><<<nb, TB, 0, stream>>>(rowStart, deg, colIdx, h1, as1, ad1, b1, o1, N);

  // layer 2: in=16, H=2, C=4
  k_node<16, 2, 4><<<nb, TB, 0, stream>>>(o1, W2, as2w, ad2w, h2, as2, ad2, N);
  k_edge<2, 4, true><<<nb, TB, 0, stream>>>(rowStart, deg, colIdx, h2, as2, ad2, b2, o2, N);

  // layer 3: in=8, H=1, C=4 + fused classifier
  k_node<8, 1, 4><<<nb, TB, 0, stream>>>(o2, W3, as3w, ad3w, h3, as3, ad3, N);
  k_edge3<<<nb, TB, 0, stream>>>(rowStart, deg, colIdx, h3, as3, ad3, b3, Wc, bc, out, N);
}

// Round 2
// 491.260 us; speedup vs baseline: 1.8601x; 1.8601x over previous
//
#include <hip/hip_runtime.h>

#define TB 256
#define NGRP 8            // XCDs on MI355X; blockIdx%8 round-robins across XCDs
#define SCAN_T 256
#define SCAN_NPT 2
#define SCAN_NPB (SCAN_T * SCAN_NPT)

static __device__ __forceinline__ float leaky(float x) {
  return x > 0.f ? x : 0.2f * x;
}

// ---------------- CSR build ----------------

__global__ void k_hist(const int* __restrict__ dstA, int* __restrict__ deg, int E) {
  int i = blockIdx.x * blockDim.x + threadIdx.x;
  if (i < E) atomicAdd(&deg[dstA[i]], 1);
}

// per-block partial sums of deg
__global__ void k_scan1(const int* __restrict__ deg, int* __restrict__ part, int N) {
  __shared__ int red[SCAN_T];
  const int t = threadIdx.x;
  const int base = blockIdx.x * SCAN_NPB + t * SCAN_NPT;
  int s = 0;
#pragma unroll
  for (int i = 0; i < SCAN_NPT; ++i) {
    int idx = base + i;
    if (idx < N) s += deg[idx];
  }
  red[t] = s;
  __syncthreads();
  for (int off = SCAN_T / 2; off > 0; off >>= 1) {
    if (t < off) red[t] += red[t + off];
    __syncthreads();
  }
  if (t == 0) part[blockIdx.x] = red[0];
}

// single-block exclusive scan of partials (nb <= 1024)
__global__ void k_scan2(int* __restrict__ part, int nb) {
  __shared__ int sh[1024];
  const int t = threadIdx.x;
  sh[t] = (t < nb) ? part[t] : 0;
  __syncthreads();
  for (int off = 1; off < 1024; off <<= 1) {
    int v = (t >= off) ? sh[t - off] : 0;
    __syncthreads();
    sh[t] += v;
    __syncthreads();
  }
  if (t < nb) part[t] = (t == 0) ? 0 : sh[t - 1];
}

// per-block exclusive scan + offset -> rowStart, cursor
__global__ void k_scan3(const int* __restrict__ deg, const int* __restrict__ part,
                        int* __restrict__ rowStart, int* __restrict__ cursor, int N) {
  __shared__ int sh[SCAN_T];
  const int t = threadIdx.x;
  const int base = blockIdx.x * SCAN_NPB + t * SCAN_NPT;
  int v[SCAN_NPT];
  int s = 0;
#pragma unroll
  for (int i = 0; i < SCAN_NPT; ++i) {
    int idx = base + i;
    v[i] = (idx < N) ? deg[idx] : 0;
    s += v[i];
  }
  sh[t] = s;
  __syncthreads();
  for (int off = 1; off < SCAN_T; off <<= 1) {
    int u = (t >= off) ? sh[t - off] : 0;
    __syncthreads();
    sh[t] += u;
    __syncthreads();
  }
  int excl = ((t == 0) ? 0 : sh[t - 1]) + part[blockIdx.x];
#pragma unroll
  for (int i = 0; i < SCAN_NPT; ++i) {
    int idx = base + i;
    if (idx < N) {
      rowStart[idx] = excl;
      cursor[idx] = excl;
      excl += v[i];
    }
  }
}

// XCD-ranged fill: group g = blockIdx%NGRP handles dst in [g*R, (g+1)*R).
// Its cursor + colIdx region (~1.6 MB) stays in that XCD's L2, so each colIdx
// line is written back once instead of ~16x from random XCDs.
__global__ void k_fill_r(const int* __restrict__ srcA, const int* __restrict__ dstA,
                         int* __restrict__ cursor, int* __restrict__ colIdx, int E, int R) {
  const int g = blockIdx.x & (NGRP - 1);
  const int lb = blockIdx.x / NGRP;
  const int nbg = gridDim.x / NGRP;
  const int lo = g * R, hi = lo + R;
  const int stride = nbg * blockDim.x;
  for (int i = lb * blockDim.x + threadIdx.x; i < E; i += stride) {
    int d = dstA[i];
    if (d >= lo && d < hi) {
      int pos = atomicAdd(&cursor[d], 1);
      colIdx[pos] = srcA[i];
    }
  }
}

// ---------------- node transform: h = x@W, alpha_src/dst ----------------

template <int IN, int H, int C>
__global__ void k_node(const float* __restrict__ xin, const float* __restrict__ W,
                       const float* __restrict__ a_src, const float* __restrict__ a_dst,
                       float* __restrict__ hout, float* __restrict__ as_,
                       float* __restrict__ ad_, int N) {
  constexpr int OUT = H * C;
  __shared__ float Ws[IN * OUT];
  __shared__ float As[OUT], Ad[OUT];
  for (int i = threadIdx.x; i < IN * OUT; i += blockDim.x) Ws[i] = W[i];
  if (threadIdx.x < OUT) {
    As[threadIdx.x] = a_src[threadIdx.x];
    Ad[threadIdx.x] = a_dst[threadIdx.x];
  }
  __syncthreads();
  int n = blockIdx.x * blockDim.x + threadIdx.x;
  if (n >= N) return;
  float acc[OUT];
#pragma unroll
  for (int j = 0; j < OUT; ++j) acc[j] = 0.f;
  const float4* x4 = reinterpret_cast<const float4*>(xin + (size_t)n * IN);
#pragma unroll
  for (int k4 = 0; k4 < IN / 4; ++k4) {
    float4 xv = x4[k4];
#pragma unroll
    for (int j = 0; j < OUT; ++j) {
      acc[j] += xv.x * Ws[(4 * k4 + 0) * OUT + j];
      acc[j] += xv.y * Ws[(4 * k4 + 1) * OUT + j];
      acc[j] += xv.z * Ws[(4 * k4 + 2) * OUT + j];
      acc[j] += xv.w * Ws[(4 * k4 + 3) * OUT + j];
    }
  }
  float4* h4 = reinterpret_cast<float4*>(hout + (size_t)n * OUT);
#pragma unroll
  for (int j4 = 0; j4 < OUT / 4; ++j4) {
    float4 v;
    v.x = acc[4 * j4 + 0];
    v.y = acc[4 * j4 + 1];
    v.z = acc[4 * j4 + 2];
    v.w = acc[4 * j4 + 3];
    h4[j4] = v;
  }
#pragma unroll
  for (int hh = 0; hh < H; ++hh) {
    float ss = 0.f, dd = 0.f;
#pragma unroll
    for (int c = 0; c < C; ++c) {
      ss += acc[hh * C + c] * As[hh * C + c];
      dd += acc[hh * C + c] * Ad[hh * C + c];
    }
    as_[n * H + hh] = ss;
    ad_[n * H + hh] = dd;
  }
}

// ---------------- edge aggregation: L lanes per node, float4 per lane ----------------
// Lane j of node n owns output floats [4j, 4j+4). Gathers by the L lanes of a
// node are consecutive float4s -> coalesced 16*L bytes. Online softmax state
// (m, s) kept redundantly per lane for its head.

template <int H, int C, int L, bool RELU>
__global__ void k_edge_ml(const int* __restrict__ rowStart, const int* __restrict__ deg,
                          const int* __restrict__ colIdx, const float* __restrict__ hfeat,
                          const float* __restrict__ as_, const float* __restrict__ ad_,
                          const float* __restrict__ bias, float* __restrict__ out, int N) {
  constexpr int OUT = H * C;
  static_assert(OUT == L * 4, "lane layout");
  int tid = blockIdx.x * blockDim.x + threadIdx.x;
  int n = tid / L;
  int j = tid & (L - 1);
  if (n >= N) return;
  const int hh = (j * 4) / C;  // head owning this lane's chunk
  float adv = ad_[n * H + hh];
  float m = leaky(as_[n * H + hh] + adv);  // self-loop term
  float s = 1.f;
  float4 acc = reinterpret_cast<const float4*>(hfeat + (size_t)n * OUT)[j];
  const int start = rowStart[n];
  const int cnt = deg[n];
  for (int i = 0; i < cnt; ++i) {
    int src = colIdx[start + i];
    float4 hv = reinterpret_cast<const float4*>(hfeat + (size_t)src * OUT)[j];
    float e = leaky(as_[src * H + hh] + adv);
    float nm = fmaxf(m, e);
    float f = __expf(m - nm);
    float p = __expf(e - nm);
    m = nm;
    s = s * f + p;
    acc.x = acc.x * f + p * hv.x;
    acc.y = acc.y * f + p * hv.y;
    acc.z = acc.z * f + p * hv.z;
    acc.w = acc.w * f + p * hv.w;
  }
  float inv = 1.f / (s + 1e-16f);
  float4 bb = reinterpret_cast<const float4*>(bias)[j];
  float4 o;
  o.x = acc.x * inv + bb.x;
  o.y = acc.y * inv + bb.y;
  o.z = acc.z * inv + bb.z;
  o.w = acc.w * inv + bb.w;
  if (RELU) {
    o.x = fmaxf(o.x, 0.f);
    o.y = fmaxf(o.y, 0.f);
    o.z = fmaxf(o.z, 0.f);
    o.w = fmaxf(o.w, 0.f);
  }
  reinterpret_cast<float4*>(out + (size_t)n * OUT)[j] = o;
}

// ---------------- layer-3 edge aggregation + fused classifier ----------------

__global__ void k_edge3(const int* __restrict__ rowStart, const int* __restrict__ deg,
                        const int* __restrict__ colIdx, const float* __restrict__ hfeat,
                        const float* __restrict__ as_, const float* __restrict__ ad_,
                        const float* __restrict__ b3, const float* __restrict__ Wc,
                        const float* __restrict__ bc, float* __restrict__ out, int N) {
  int n = blockIdx.x * blockDim.x + threadIdx.x;
  if (n >= N) return;
  float adv = ad_[n];
  float m = leaky(as_[n] + adv);
  float s = 1.f;
  float4 hn = reinterpret_cast<const float4*>(hfeat)[n];
  float acc0 = hn.x, acc1 = hn.y, acc2 = hn.z, acc3 = hn.w;
  const int start = rowStart[n];
  const int cnt = deg[n];
  for (int i = 0; i < cnt; ++i) {
    int src = colIdx[start + i];
    float4 hv = reinterpret_cast<const float4*>(hfeat)[src];
    float e = leaky(as_[src] + adv);
    float nm = fmaxf(m, e);
    float f = __expf(m - nm);
    float p = __expf(e - nm);
    m = nm;
    s = s * f + p;
    acc0 = acc0 * f + p * hv.x;
    acc1 = acc1 * f + p * hv.y;
    acc2 = acc2 * f + p * hv.z;
    acc3 = acc3 * f + p * hv.w;
  }
  float inv = 1.f / (s + 1e-16f);
  float o0 = acc0 * inv + b3[0];
  float o1 = acc1 * inv + b3[1];
  float o2 = acc2 * inv + b3[2];
  float o3 = acc3 * inv + b3[3];
  float r0 = o0 * Wc[0] + o1 * Wc[2] + o2 * Wc[4] + o3 * Wc[6] + bc[0];
  float r1 = o0 * Wc[1] + o1 * Wc[3] + o2 * Wc[5] + o3 * Wc[7] + bc[1];
  out[(size_t)n * 2 + 0] = r0;
  out[(size_t)n * 2 + 1] = r1;
}

// ---------------- launch ----------------

extern "C" void kernel_launch(void* const* d_in, const int* in_sizes, int n_in,
                              void* d_out, int out_size, void* d_ws, size_t ws_size,
                              hipStream_t stream) {
  const float* x    = (const float*)d_in[0];
  const int*   ei   = (const int*)d_in[1];
  const float* W1   = (const float*)d_in[2];
  const float* as1w = (const float*)d_in[3];
  const float* ad1w = (const float*)d_in[4];
  const float* b1   = (const float*)d_in[5];
  const float* W2   = (const float*)d_in[6];
  const float* as2w = (const float*)d_in[7];
  const float* ad2w = (const float*)d_in[8];
  const float* b2   = (const float*)d_in[9];
  const float* W3   = (const float*)d_in[10];
  const float* as3w = (const float*)d_in[11];
  const float* ad3w = (const float*)d_in[12];
  const float* b3   = (const float*)d_in[13];
  const float* Wc   = (const float*)d_in[14];
  const float* bc   = (const float*)d_in[15];
  float* out = (float*)d_out;

  const int N = in_sizes[0] / 128;
  const int E = in_sizes[1] / 2;
  const int* srcA = ei;
  const int* dstA = ei + E;

  char* p = (char*)d_ws;
  auto alloc = [&](size_t bytes) -> void* {
    void* r = (void*)p;
    p += (bytes + 255) & ~(size_t)255;
    return r;
  };
  int* deg      = (int*)alloc((size_t)N * 4);
  int* rowStart = (int*)alloc((size_t)N * 4);
  int* cursor   = (int*)alloc((size_t)N * 4);
  int* part     = (int*)alloc(1024 * 4);
  int* colIdx   = (int*)alloc((size_t)E * 4);
  float* h1  = (float*)alloc((size_t)N * 16 * 4);
  float* as1 = (float*)alloc((size_t)N * 2 * 4);
  float* ad1 = (float*)alloc((size_t)N * 2 * 4);
  float* o1  = (float*)alloc((size_t)N * 16 * 4);
  float* h2  = (float*)alloc((size_t)N * 8 * 4);
  float* as2 = (float*)alloc((size_t)N * 2 * 4);
  float* ad2 = (float*)alloc((size_t)N * 2 * 4);
  float* o2  = (float*)alloc((size_t)N * 8 * 4);
  float* h3  = (float*)alloc((size_t)N * 4 * 4);
  float* as3 = (float*)alloc((size_t)N * 4);
  float* ad3 = (float*)alloc((size_t)N * 4);

  hipMemsetAsync(deg, 0, (size_t)N * 4, stream);

  const int eb = (E + TB - 1) / TB;
  const int nb = (N + TB - 1) / TB;
  const int sb = (N + SCAN_NPB - 1) / SCAN_NPB;   // <= 1024
  const int R  = (N + NGRP - 1) / NGRP;

  k_hist<<<eb, TB, 0, stream>>>(dstA, deg, E);
  k_scan1<<<sb, SCAN_T, 0, stream>>>(deg, part, N);
  k_scan2<<<1, 1024, 0, stream>>>(part, sb);
  k_scan3<<<sb, SCAN_T, 0, stream>>>(deg, part, rowStart, cursor, N);
  k_fill_r<<<1024, TB, 0, stream>>>(srcA, dstA, cursor, colIdx, E, R);

  // layer 1: in=128, H=2, C=8 (4 lanes/node)
  k_node<128, 2, 8><<<nb, TB, 0, stream>>>(x, W1, as1w, ad1w, h1, as1, ad1, N);
  k_edge_ml<2, 8, 4, true><<<(N * 4 + TB - 1) / TB, TB, 0, stream>>>(rowStart, deg, colIdx, h1, as1, ad1, b1, o1, N);

  // layer 2: in=16, H=2, C=4 (2 lanes/node)
  k_node<16, 2, 4><<<nb, TB, 0, stream>>>(o1, W2, as2w, ad2w, h2, as2, ad2, N);
  k_edge_ml<2, 4, 2, true><<<(N * 2 + TB - 1) / TB, TB, 0, stream>>>(rowStart, deg, colIdx, h2, as2, ad2, b2, o2, N);

  // layer 3: in=8, H=1, C=4 + fused classifier
  k_node<8, 1, 4><<<nb, TB, 0, stream>>>(o2, W3, as3w, ad3w, h3, as3, ad3, N);
  k_edge3<<<nb, TB, 0, stream>>>(rowStart, deg, colIdx, h3, as3, ad3, b3, Wc, bc, out, N);
}